// Round 4
// baseline (22.781 us; speedup 1.0000x reference)
//
#include <hip/hip_runtime.h>

#define BINS 32
#define OUT_PER_ROW (BINS * BINS * BINS)   // 32768
#define WORDS (OUT_PER_ROW / 2)            // 16384 packed u32 (2 x u16 counts)
#define THREADS 1024

// Exact slow path: idx = #{ edges[j] < x : j in [1, BINS-1] }
// (== searchsorted(edges[1:-1], x, 'left')). Arithmetic guess (within +-1 for
// these near-uniform edges) + one-step fixup against ACTUAL edge values.
// se[i], se[i+1] adjacent -> single ds_read2_b32.
__device__ __forceinline__ int bucket_exact(float x, const float* __restrict__ se,
                                            float e0, float scale) {
    float t = fminf(fmaxf((x - e0) * scale, 0.0f), (float)(BINS - 1));
    int i = (int)t;
    const float f0 = se[i];
    const float f1 = se[i + 1];
    const int up = (int)(i < BINS - 1) & (int)(f1 < x);
    i += up;
    const float fi = up ? f1 : f0;           // == se[i] at the new i
    i -= (int)(i > 0) & (int)(fi >= x);
    return i;
}

// Fast path: pure-arithmetic bin, provably exact whenever t=(x-e0)*scale is
// farther than eps from every internal integer edge index k in [1,31].
// eps is derived at runtime from the ACTUAL edge values (delta_max below), so
// no assumption about how linspace rounded — exactness is guaranteed.
// Whole-wave fallback to the LDS-exact path only if any lane is near an edge
// (probability ~1e-4 per bucket -> branch almost never taken).
__device__ __forceinline__ int bucket(float x, const float* __restrict__ se,
                                      float e0, float scale, float eps) {
    const float t = (x - e0) * scale;
    const float rt = rintf(t);
    const bool near_edge = (fabsf(t - rt) <= eps) & (rt >= 1.0f) & (rt <= 31.0f);
    if (__builtin_expect(__ballot((int)near_edge) != 0ull, 0)) {
        return bucket_exact(x, se, e0, scale);   // wave-uniform, exact
    }
    return min(max((int)floorf(t), 0), BINS - 1);
}

// Swizzle of packed-word index to decorrelate LDS atomic banks from the
// Gaussian-center-hot low bin bits. Keeps low 2 bits (uint2/uint4 alignment).
__device__ __forceinline__ int swz(int w) {
    return w ^ (((w >> 5) & 7) << 2);
}

// 8 waves/SIMD: forces VGPR <= 64 so the LDS-allowed 2 blocks/CU
// (32 waves/CU) is actually reached.
__global__ __launch_bounds__(THREADS, 8)
void bin_density_kernel(const float* __restrict__ states,
                        const float* __restrict__ edges,
                        float* __restrict__ out, int N) {
    __shared__ unsigned int hist[WORDS];   // 64 KiB
    __shared__ float se[BINS + 1];

    const int tid = threadIdx.x;
    const int b = blockIdx.x;

    if (tid < BINS + 1) se[tid] = edges[tid];

    // zero the histogram (4 x uint4 per thread)
    uint4* h4 = reinterpret_cast<uint4*>(hist);
#pragma unroll
    for (int j = 0; j < WORDS / 4 / THREADS; ++j)
        h4[tid + j * THREADS] = uint4{0u, 0u, 0u, 0u};

    __syncthreads();

    const float e0 = se[0];
    const float scale = (float)BINS / (se[BINS] - e0);

    // Runtime safety radius: how far the actual edges deviate from the ideal
    // uniform grid, in t-units, plus fp32 rounding margin for t itself.
    float dmax = 0.0f;
#pragma unroll
    for (int k = 1; k < BINS; ++k)
        dmax = fmaxf(dmax, fabsf((se[k] - e0) * scale - (float)k));
    const float eps = dmax * 1.01f + 3e-5f;

    // 4 samples (12 floats) per group via 3 x float4 loads; N=8192 -> exactly
    // 2 groups per thread, fully unrolled.
    const float4* sp4 = reinterpret_cast<const float4*>(states + (long long)b * N * 3);
    const int groups = N / 4;
#pragma unroll 2
    for (int g = tid; g < groups; g += THREADS) {
        const float4 a = sp4[3 * g + 0];
        const float4 c = sp4[3 * g + 1];
        const float4 d = sp4[3 * g + 2];

        const int l0 = bucket(a.x, se, e0, scale, eps)
                     + BINS * bucket(a.y, se, e0, scale, eps)
                     + BINS * BINS * bucket(a.z, se, e0, scale, eps);
        const int l1 = bucket(a.w, se, e0, scale, eps)
                     + BINS * bucket(c.x, se, e0, scale, eps)
                     + BINS * BINS * bucket(c.y, se, e0, scale, eps);
        const int l2 = bucket(c.z, se, e0, scale, eps)
                     + BINS * bucket(c.w, se, e0, scale, eps)
                     + BINS * BINS * bucket(d.x, se, e0, scale, eps);
        const int l3 = bucket(d.y, se, e0, scale, eps)
                     + BINS * bucket(d.z, se, e0, scale, eps)
                     + BINS * BINS * bucket(d.w, se, e0, scale, eps);

        // packed u16 pair per u32 word (counts <= 8192, no carry); word index
        // swizzled to spread hot banks.
        atomicAdd(&hist[swz(l0 >> 1)], 1u << ((l0 & 1) << 4));
        atomicAdd(&hist[swz(l1 >> 1)], 1u << ((l1 & 1) << 4));
        atomicAdd(&hist[swz(l2 >> 1)], 1u << ((l2 & 1) << 4));
        atomicAdd(&hist[swz(l3 >> 1)], 1u << ((l3 & 1) << 4));
    }

    __syncthreads();

    // write out: 2 packed words -> float4, perfectly lane-coalesced stores.
    // uint2 at word pair {2m, 2m+1}; swizzled location of the pair is
    // contiguous & even, so read h2[m ^ (((m>>4)&7)<<1)].
    const float invn = 1.0f / (float)N;
    float4* orow = reinterpret_cast<float4*>(out + (long long)b * OUT_PER_ROW);
    const uint2* h2 = reinterpret_cast<const uint2*>(hist);
#pragma unroll
    for (int j = 0; j < OUT_PER_ROW / 4 / THREADS; ++j) {
        const int m = tid + j * THREADS;
        const uint2 w = h2[m ^ (((m >> 4) & 7) << 1)];
        float4 v;
        v.x = (float)(w.x & 0xFFFFu) * invn;
        v.y = (float)(w.x >> 16) * invn;
        v.z = (float)(w.y & 0xFFFFu) * invn;
        v.w = (float)(w.y >> 16) * invn;
        orow[m] = v;
    }
}

extern "C" void kernel_launch(void* const* d_in, const int* in_sizes, int n_in,
                              void* d_out, int out_size, void* d_ws, size_t ws_size,
                              hipStream_t stream) {
    const float* states = (const float*)d_in[0];
    const float* edges = (const float*)d_in[1];
    float* out = (float*)d_out;

    const int B = out_size / OUT_PER_ROW;          // 512
    const int N = in_sizes[0] / (3 * B);           // 8192

    bin_density_kernel<<<B, THREADS, 0, stream>>>(states, edges, out, N);
}